// Round 10
// baseline (197.766 us; speedup 1.0000x reference)
//
#include <hip/hip_runtime.h>
#include <math.h>

// PhysQuadModel: batched RK4 rollout of quadrotor dynamics.
// Ladder (rocprof): R6 192 | R7 125 | R8 203 | R9 140 | R10 136 | R11 114
//   | R12 95 (3-wave pipeline) | R13 86 (4-wave pipeline, K=4, barriers).
// R13 decomposition: critical-wave stream ~430-500 cyc/step, but wall 807
//   -> ~300-375 cyc/step is __syncthreads rendezvous (lgkm drain + barrier
//   + post-barrier LDS latency re-exposure, x67 slots, all waves lockstep).
// R14 (this): SAME 4-wave split, SAME buffers, SAME math (bit-identical to
//   R13) -- only the sync changes: per-wave LDS progress counters + spin
//   (volatile read + s_sleep) + __threadfence_block. Bounded-buffer wait
//   conditions (slots already = lag+1):
//     w0(g): prog1,2,3 >= g-3   (obuf reuse)
//     w1(g): prog0 >= g+1; prog2,3 >= g-2   (qbuf reuse)
//     w2(g): prog1 >= g+1; prog3 >= g-1     (vbuf reuse)
//     w3(g): prog2 >= g+1
//   Downstream waits are data-ready; upstream waits bounded-buffer -> no
//   deadlock; monotonic ints. Steady state: waves free-run with ~1-group
//   skew, poll cost ~1 LDS round-trip/group (~30 cyc/step vs ~300).

namespace {
constexpr int   kB    = 8192;
constexpr int   kN    = 256;
constexpr float kDT   = 0.01f;
constexpr float kMG   = 0.033f * 9.81f;        // M*G
constexpr float kTmax = 1.9f * 0.033f * 9.81f; // 0.6150870
constexpr float kKT   = 3.8e-08f;
constexpr float kKC   = 3.8e-11f;
constexpr float kKTA  = kKT * 0.04f;           // KT*ARM
constexpr float kInvM = 1.0f / 0.033f;
constexpr float kJx   = 1.4e-05f, kJz = 2.17e-05f;
constexpr float kInvJx = 1.0f / 1.4e-05f;
constexpr float kInvJz = 1.0f / 2.17e-05f;
constexpr float kA    = (kJz - kJx) * kInvJx;  // 0.55 (Jx==Jy)
constexpr float kTq0  = 0.009f, kTq1 = 0.009f, kTq2 = 0.002f;
constexpr float kH    = 0.005f;                // 0.5*dt   (omega euler)
constexpr float kHq   = 0.0025f;               // 0.5*dt*0.5 (qd' = 2*qd)
constexpr float kDTq  = 0.005f;                // dt*0.5   (stage-4 quat)
constexpr float kDT6  = 0.0016666667f;         // dt/6
constexpr float kDT6q = 0.5f * kDT6;           // dt/12
constexpr float kVC   = kDT6 * kInvM;          // raw accel -> vel
constexpr float kPC   = kDT6 * kDT * kInvM;    // raw accel -> pos
}

typedef float v2 __attribute__((ext_vector_type(2)));

__device__ __forceinline__ v2 mk2(float a, float b) { v2 r; r.x = a; r.y = b; return r; }
__device__ __forceinline__ float fast_rcp(float x) { return __builtin_amdgcn_rcpf(x); }
__device__ __forceinline__ float fast_rsq(float x) { return __builtin_amdgcn_rsqf(x); }

// atan2 for y >= 0, result in [0, pi]. Minimax atan poly on [0,1], err ~1e-5.
__device__ __forceinline__ float atan2_pos(float y, float x) {
  float axx = fabsf(x);
  float mn  = fminf(y, axx);
  float mx  = fmaxf(y, axx);
  float t   = mn * fast_rcp(mx);
  float t2  = t * t;
  float p = fmaf(t2, -0.01172120f, 0.05265332f);
  p = fmaf(t2, p, -0.11643287f);
  p = fmaf(t2, p, 0.19354346f);
  p = fmaf(t2, p, -0.33262347f);
  p = fmaf(t2, p, 0.99997726f);
  p *= t;
  p = (y > axx) ? (1.5707963268f - p) : p;
  p = (x < 0.0f) ? (3.1415926536f - p) : p;
  return p;
}

// accurate, used ONCE per trajectory at init
__device__ __forceinline__ void so3_to_quat_init(float rx, float ry, float rz,
                                                 float& qx, float& qy, float& qz, float& qw) {
  float theta = sqrtf(rx * rx + ry * ry + rz * rz);
  float half  = 0.5f * theta;
  float s     = sinf(half);
  float c     = cosf(half);
  float k     = s / (theta + 1e-8f);
  bool  small = theta < 1e-6f;
  k  = small ? 0.5f : k;
  qw = small ? 1.0f : c;
  qx = k * rx; qy = k * ry; qz = k * rz;
}

// log map, output-only path (w3)
__device__ __forceinline__ void quat_to_so3_fast(float qx, float qy, float qz, float qw,
                                                 float& rx, float& ry, float& rz) {
  float nv2 = qx * qx + qy * qy + qz * qz;
  float nv  = nv2 * fast_rsq(fmaxf(nv2, 1e-20f));   // sqrt(nv2), safe at 0
  float wc  = fminf(fmaxf(qw, -0.999999f), 0.999999f);
  float ang = 2.0f * atan2_pos(nv, wc);
  float k   = ang * fast_rcp(nv + 1e-6f);
  k = (nv < 1e-6f) ? 2.0f : k;
  rx = k * qx; ry = k * qy; rz = k * qz;
}

// Newton renorm from y0=1 (|q|^2 = 1+eps): no transcendental.
__device__ __forceinline__ void renorm(v2& a, v2& b) {
  v2 s = a * a + b * b;
  float c = 1.5f - 0.5f * (s.x + s.y);
  a *= c; b *= c;
}

// quat derivative (x2)
__device__ __forceinline__ void qd_calc(
    v2 q_xy, v2 q_zw, v2 w_xy, float wz, v2& qd_xy, v2& qd_zw) {
  float qx = q_xy.x, qy = q_xy.y, qz = q_zw.x, qw = q_zw.y;
  v2 aq = mk2(qy, -qx);
  v2 pw = mk2(-w_xy.y, w_xy.x);
  qd_xy = qw * w_xy + wz * aq + qz * pw;
  qd_zw = wz * mk2(qw, -qz) + qx * mk2(w_xy.y, -w_xy.x) - qy * w_xy;
}

// accel from a stage quat (raw, 1/M deferred).
__device__ __forceinline__ void acc_q(float qx, float qy, float qz, float qw,
                                      float T2, float TmG,
                                      v2& a_xy, float& az) {
  v2 t_xy = T2 * mk2(qy, -qx);
  a_xy = qw * t_xy + qz * mk2(-t_xy.y, t_xy.x);
  az   = TmG - T2 * (qx * qx + qy * qy);
}

// ---------------- w0: omega + tau, one RK4 step ---------------------
__device__ __forceinline__ void omega_step(
    float4 u, v2& o_xy, float& oz, float4* dst) {
  float m20 = u.x * u.x, m21 = u.y * u.y, m22 = u.z * u.z, m23 = u.w * u.w;
  float sa = m20 + m21, sb = m22 + m23;
  float T   = fminf(kKT * (sa + sb), kTmax);
  float tq1 = kKTA * (sb - sa);
  float tq2 = kKTA * ((m21 + m22) - (m20 + m23));
  float tq3 = kKC  * ((m20 + m22) - (m21 + m23));
  tq1 = __builtin_amdgcn_fmed3f(tq1, -kTq0, kTq0);
  tq2 = __builtin_amdgcn_fmed3f(tq2, -kTq1, kTq1);
  tq3 = __builtin_amdgcn_fmed3f(tq3, -kTq2, kTq2);
  v2    s_xy = mk2(tq1 * kInvJx, tq2 * kInvJx);
  float wdz  = tq3 * kInvJz;          // stage-invariant (Jx==Jy)
  float ozh  = fmaf(kH,  wdz, oz);
  float ozf  = fmaf(kDT, wdz, oz);
  v2 wd1 = s_xy + (kA * oz ) * mk2(-o_xy.y, o_xy.x);
  v2 o2  = o_xy + kH * wd1;
  v2 wd2 = s_xy + (kA * ozh) * mk2(-o2.y, o2.x);
  v2 o3  = o_xy + kH * wd2;
  v2 wd3 = s_xy + (kA * ozh) * mk2(-o3.y, o3.x);
  v2 o4  = o_xy + kDT * wd3;
  v2 wd4 = s_xy + (kA * ozf) * mk2(-o4.y, o4.x);
  dst[0 * 64] = make_float4(o_xy.x, o_xy.y, oz, ozh);
  dst[1 * 64] = make_float4(o2.x, o2.y, o3.x, o3.y);
  dst[2 * 64] = make_float4(o4.x, o4.y, ozf, T);
  v2 ws = wd2 + wd3;
  o_xy = o_xy + kDT6 * ((wd1 + ws) + (ws + wd4));
  oz = ozf;
  dst[3 * 64] = make_float4(o_xy.x, o_xy.y, oz, 0.0f);
}

// ---------------- w1: quat chain, NO stage renorms (R10a-proven) ----
__device__ __forceinline__ void quat_step_nr(
    const float4* src, v2& q_xy, v2& q_zw, float4* dst) {
  float4 F0 = src[0 * 64], F1 = src[1 * 64], F2 = src[2 * 64];
  v2 o1 = mk2(F0.x, F0.y); float oz1 = F0.z, ozh = F0.w;
  v2 o2 = mk2(F1.x, F1.y), o3 = mk2(F1.z, F1.w);
  v2 o4 = mk2(F2.x, F2.y); float ozf = F2.z;

  v2 qd1_xy, qd1_zw;
  qd_calc(q_xy, q_zw, o1, oz1, qd1_xy, qd1_zw);
  v2 q2_xy = q_xy + kHq * qd1_xy, q2_zw = q_zw + kHq * qd1_zw;
  v2 qd2_xy, qd2_zw;
  qd_calc(q2_xy, q2_zw, o2, ozh, qd2_xy, qd2_zw);
  v2 q3_xy = q_xy + kHq * qd2_xy, q3_zw = q_zw + kHq * qd2_zw;
  v2 qd3_xy, qd3_zw;
  qd_calc(q3_xy, q3_zw, o3, ozh, qd3_xy, qd3_zw);
  v2 q4_xy = q_xy + kDTq * qd3_xy, q4_zw = q_zw + kDTq * qd3_zw;
  v2 qd4_xy, qd4_zw;
  qd_calc(q4_xy, q4_zw, o4, ozf, qd4_xy, qd4_zw);

  dst[0 * 64] = make_float4(q2_xy.x, q2_xy.y, q2_zw.x, q2_zw.y);
  dst[1 * 64] = make_float4(q3_xy.x, q3_xy.y, q3_zw.x, q3_zw.y);
  dst[2 * 64] = make_float4(q4_xy.x, q4_xy.y, q4_zw.x, q4_zw.y);
  v2 qxy23 = qd2_xy + qd3_xy;
  q_xy = q_xy + kDT6q * ((qd1_xy + qxy23) + (qxy23 + qd4_xy));
  v2 qzw23 = qd2_zw + qd3_zw;
  q_zw = q_zw + kDT6q * ((qd1_zw + qzw23) + (qzw23 + qd4_zw));
  renorm(q_xy, q_zw);               // loop-carried renorm kept
  dst[3 * 64] = make_float4(q_xy.x, q_xy.y, q_zw.x, q_zw.y);
}

// ---------------- w2: accels + p/v + ov0 store; ships (vy,vz) -------
__device__ __forceinline__ void accpv_step(
    const float4* qsrc, const float4* osrc, float4* vdst,
    v2& p_xy, float& pz, v2& v_xy, float& vz,
    float& qpx, float& qpy, float& qpz, float& qpw,
    float4* ovp) {
  float4 Q2 = qsrc[0 * 64], Q3 = qsrc[1 * 64], Q4 = qsrc[2 * 64], QN = qsrc[3 * 64];
  float T  = osrc[2 * 64].w;
  float T2 = T + T, TmG = T - kMG;

  v2 a1, a2, a3, a4; float az1, az2, az3, az4;
  acc_q(qpx, qpy, qpz, qpw, T2, TmG, a1, az1);
  acc_q(Q2.x, Q2.y, Q2.z, Q2.w, T2, TmG, a2, az2);
  acc_q(Q3.x, Q3.y, Q3.z, Q3.w, T2, TmG, a3, az3);
  acc_q(Q4.x, Q4.y, Q4.z, Q4.w, T2, TmG, a4, az4);

  v2 t23 = a2 + a3;
  v2 Apos = a1 + t23;
  v2 Avel = Apos + t23 + a4;
  p_xy = p_xy + kDT * v_xy;  p_xy = p_xy + kPC * Apos;
  float az23 = az2 + az3;
  float Aposz = az1 + az23;
  float Avelz = Aposz + az23 + az4;
  pz = fmaf(kDT, vz, pz);  pz = fmaf(kPC, Aposz, pz);
  v_xy = v_xy + kVC * Avel;
  vz   = fmaf(kVC, Avelz, vz);

  ovp[0]   = make_float4(p_xy.x, p_xy.y, pz, v_xy.x);
  vdst[0]  = make_float4(v_xy.y, vz, 0.0f, 0.0f);

  qpx = QN.x; qpy = QN.y; qpz = QN.z; qpw = QN.w;
}

// ---------------- w3: logmap + ov1/ov2 stores -----------------------
__device__ __forceinline__ void logst_step(
    const float4* qsrc, const float4* osrc, const float4* vsrc, float4* ovp) {
  float4 QN = qsrc[3 * 64];
  float4 OM = osrc[3 * 64];
  float4 V  = vsrc[0];
  float rx, ry, rz;
  quat_to_so3_fast(QN.x, QN.y, QN.z, QN.w, rx, ry, rz);
  ovp[1] = make_float4(V.x, V.y, rx, ry);
  ovp[2] = make_float4(rz, OM.x, OM.y, OM.z);
}

// spin-wait helpers (flags are broadcast LDS reads; monotonic counters)
__device__ __forceinline__ void wait1(volatile int* prog, int i0, int v0) {
  while (prog[i0] < v0) __builtin_amdgcn_s_sleep(1);
}
__device__ __forceinline__ void wait2(volatile int* prog, int i0, int v0,
                                      int i1, int v1) {
  while (prog[i0] < v0 || prog[i1] < v1) __builtin_amdgcn_s_sleep(1);
}
__device__ __forceinline__ void wait3(volatile int* prog, int i0, int v0,
                                      int i1, int v1, int i2, int v2) {
  while (prog[i0] < v0 || prog[i1] < v1 || prog[i2] < v2)
    __builtin_amdgcn_s_sleep(1);
}

__global__ __launch_bounds__(256) void quad_rk4_kernel(
    const float* __restrict__ x0,
    const float* __restrict__ u_seq,
    float* __restrict__ out) {
  // obuf [slot4][step4][field4][lane64]  = 64KB (lag-3 reader w3)
  // qbuf [slot3][step4][field4][lane64]  = 48KB (lag-2 reader w3)
  // vbuf [slot2][step4][lane64]          =  8KB (lag-1 reader w3)
  __shared__ float4 obuf[4 * 4 * 4 * 64];
  __shared__ float4 qbuf[3 * 4 * 4 * 64];
  __shared__ float4 vbuf[2 * 4 * 64];
  __shared__ int    prog[4];

  const int lane = threadIdx.x & 63;
  const int wid  = threadIdx.x >> 6;
  const int b    = blockIdx.x * 64 + lane;
  volatile int* pr = prog;

  if (threadIdx.x == 0) { prog[0] = 0; prog[1] = 0; prog[2] = 0; prog[3] = 0; }
  __syncthreads();    // flags initialized; ONLY barrier in the kernel

  const float4* xv = reinterpret_cast<const float4*>(x0) + (size_t)b * 3;
  float4 s0 = xv[0], s1 = xv[1], s2 = xv[2];
  const float4* uv = reinterpret_cast<const float4*>(u_seq) + (size_t)b * kN;
  float4* ov = reinterpret_cast<float4*>(out) + (size_t)b * kN * 3;

  constexpr int kG = kN / 4;           // 64 groups of 4 steps

  if (wid == 0) {
    // ============ w0: omega + tau chain ============
    v2 o_xy = mk2(s2.y, s2.z); float oz = s2.w;
    float4 ug0 = uv[0], ug1 = uv[1], ug2 = uv[2], ug3 = uv[3];
    for (int g = 0; g < kG; ++g) {
      int gn = (g + 1 < kG) ? (g + 1) * 4 : (kG - 1) * 4;
      float4 un0 = uv[gn + 0], un1 = uv[gn + 1],
             un2 = uv[gn + 2], un3 = uv[gn + 3];
      wait3(pr, 1, g - 3, 2, g - 3, 3, g - 3);   // obuf slot reuse
      __threadfence_block();
      float4* dst = &obuf[(g & 3) * 1024 + lane];
      omega_step(ug0, o_xy, oz, dst + 0 * 256);
      omega_step(ug1, o_xy, oz, dst + 1 * 256);
      omega_step(ug2, o_xy, oz, dst + 2 * 256);
      omega_step(ug3, o_xy, oz, dst + 3 * 256);
      __threadfence_block();                     // drain ds_writes
      if (lane == 0) pr[0] = g + 1;
      ug0 = un0; ug1 = un1; ug2 = un2; ug3 = un3;
    }
  } else if (wid == 1) {
    // ============ w1: quat chain ============
    float a, bb, c, d;
    so3_to_quat_init(s1.z, s1.w, s2.x, a, bb, c, d);
    v2 q_xy = mk2(a, bb), q_zw = mk2(c, d);
    for (int g = 0; g < kG; ++g) {
      wait3(pr, 0, g + 1, 2, g - 2, 3, g - 2);   // data + qbuf reuse
      __threadfence_block();
      const float4* src = &obuf[(g & 3) * 1024 + lane];
      float4*       dst = &qbuf[(g % 3) * 1024 + lane];
      quat_step_nr(src + 0 * 256, q_xy, q_zw, dst + 0 * 256);
      quat_step_nr(src + 1 * 256, q_xy, q_zw, dst + 1 * 256);
      quat_step_nr(src + 2 * 256, q_xy, q_zw, dst + 2 * 256);
      quat_step_nr(src + 3 * 256, q_xy, q_zw, dst + 3 * 256);
      __threadfence_block();
      if (lane == 0) pr[1] = g + 1;
    }
  } else if (wid == 2) {
    // ============ w2: accels + p/v + ov0 ============
    v2 p_xy = mk2(s0.x, s0.y); float pz = s0.z;
    v2 v_xy = mk2(s0.w, s1.x); float vz = s1.y;
    float qpx, qpy, qpz, qpw;
    so3_to_quat_init(s1.z, s1.w, s2.x, qpx, qpy, qpz, qpw);
    for (int g = 0; g < kG; ++g) {
      wait2(pr, 1, g + 1, 3, g - 1);             // data + vbuf reuse
      __threadfence_block();
      const float4* qsrc = &qbuf[(g % 3) * 1024 + lane];
      const float4* osrc = &obuf[(g & 3) * 1024 + lane];
      float4*       vdst = &vbuf[(g & 1) * 256 + lane];
      float4* ovp = ov + (size_t)(g * 4) * 3;
      accpv_step(qsrc + 0 * 256, osrc + 0 * 256, vdst + 0 * 64,
                 p_xy, pz, v_xy, vz, qpx, qpy, qpz, qpw, ovp + 0);
      accpv_step(qsrc + 1 * 256, osrc + 1 * 256, vdst + 1 * 64,
                 p_xy, pz, v_xy, vz, qpx, qpy, qpz, qpw, ovp + 3);
      accpv_step(qsrc + 2 * 256, osrc + 2 * 256, vdst + 2 * 64,
                 p_xy, pz, v_xy, vz, qpx, qpy, qpz, qpw, ovp + 6);
      accpv_step(qsrc + 3 * 256, osrc + 3 * 256, vdst + 3 * 64,
                 p_xy, pz, v_xy, vz, qpx, qpy, qpz, qpw, ovp + 9);
      __threadfence_block();
      if (lane == 0) pr[2] = g + 1;
    }
  } else {
    // ============ w3: logmap + ov1/ov2 ============
    for (int g = 0; g < kG; ++g) {
      wait1(pr, 2, g + 1);                       // transitively covers all
      __threadfence_block();
      const float4* qsrc = &qbuf[(g % 3) * 1024 + lane];
      const float4* osrc = &obuf[(g & 3) * 1024 + lane];
      const float4* vsrc = &vbuf[(g & 1) * 256 + lane];
      float4* ovp = ov + (size_t)(g * 4) * 3;
      logst_step(qsrc + 0 * 256, osrc + 0 * 256, vsrc + 0 * 64, ovp + 0);
      logst_step(qsrc + 1 * 256, osrc + 1 * 256, vsrc + 1 * 64, ovp + 3);
      logst_step(qsrc + 2 * 256, osrc + 2 * 256, vsrc + 2 * 64, ovp + 6);
      logst_step(qsrc + 3 * 256, osrc + 3 * 256, vsrc + 3 * 64, ovp + 9);
      if (lane == 0) pr[3] = g + 1;
    }
  }
}

extern "C" void kernel_launch(void* const* d_in, const int* in_sizes, int n_in,
                              void* d_out, int out_size, void* d_ws, size_t ws_size,
                              hipStream_t stream) {
  const float* x0    = (const float*)d_in[0];   // (8192, 12)
  const float* u_seq = (const float*)d_in[1];   // (8192, 256, 4)
  float*       out   = (float*)d_out;           // (8192, 256, 12)
  (void)in_sizes; (void)n_in; (void)out_size; (void)d_ws; (void)ws_size;

  dim3 block(256);            // w0 omega | w1 quat | w2 acc+pv | w3 log+store
  dim3 grid(kB / 64);         // 128 blocks, 64 trajectories each
  quad_rk4_kernel<<<grid, block, 0, stream>>>(x0, u_seq, out);
}

// Round 11
// 177.330 us; speedup vs baseline: 1.1152x; 1.1152x over previous
//
#include <hip/hip_runtime.h>
#include <math.h>

// PhysQuadModel: batched RK4 rollout of quadrotor dynamics.
// Ladder (rocprof): R6 192 | R7 125 | R8 203 | R9 140 | R10 136 | R11 114
//   | R12 95 | R13 86 (4-wave, K=4, barriers) | R14 104 (flag sync REGRESSED:
//   threadfence drains vmcnt(0) incl. global stores; barriers are cheaper).
// R13 model: 807 cyc/step = stream(~470) + B/K with B~1200 cyc/slot, K=4.
// R15 (this): 4-wave pipeline at K=8 (35 barriers vs 67), LDS-compressed to
//   144KB, math BIT-IDENTICAL to R13:
//   - obuf 3 fields (48KB): w1 loop-carries o1/oz1 (= w0's exact values from
//     prev step: o1(t)=o_new(t-1), oz1(t)=ozf(t-1)); ozh shipped exact.
//   - w1 forwards T+OM as qbuf field EX -> obuf single-reader, 2 slots.
//     qbuf 5 fields (80KB), readers w2+w3 at same lag -> 2 slots.
//   - w3 = logmap + ov2 store (has rz+OM), ships (rx,ry) via rbuf (16KB);
//     w2 stores ov1 one slot later from 8 buffered (vy,vz) regs.
//   Slot s: w0 grp s | w1 s-1 | w2 acc/pv s-2 + ov1-stores s-3 | w3 s-2.

namespace {
constexpr int   kB    = 8192;
constexpr int   kN    = 256;
constexpr int   kK    = 8;               // steps per group
constexpr int   kG    = kN / kK;         // 32 groups
constexpr float kDT   = 0.01f;
constexpr float kMG   = 0.033f * 9.81f;        // M*G
constexpr float kTmax = 1.9f * 0.033f * 9.81f; // 0.6150870
constexpr float kKT   = 3.8e-08f;
constexpr float kKC   = 3.8e-11f;
constexpr float kKTA  = kKT * 0.04f;           // KT*ARM
constexpr float kInvM = 1.0f / 0.033f;
constexpr float kJx   = 1.4e-05f, kJz = 2.17e-05f;
constexpr float kInvJx = 1.0f / 1.4e-05f;
constexpr float kInvJz = 1.0f / 2.17e-05f;
constexpr float kA    = (kJz - kJx) * kInvJx;  // 0.55 (Jx==Jy)
constexpr float kTq0  = 0.009f, kTq1 = 0.009f, kTq2 = 0.002f;
constexpr float kH    = 0.005f;                // 0.5*dt   (omega euler)
constexpr float kHq   = 0.0025f;               // 0.5*dt*0.5 (qd' = 2*qd)
constexpr float kDTq  = 0.005f;                // dt*0.5   (stage-4 quat)
constexpr float kDT6  = 0.0016666667f;         // dt/6
constexpr float kDT6q = 0.5f * kDT6;           // dt/12
constexpr float kVC   = kDT6 * kInvM;          // raw accel -> vel
constexpr float kPC   = kDT6 * kDT * kInvM;    // raw accel -> pos
// LDS strides (in float4 units)
constexpr int kOSlot = kK * 3 * 64;   // 1536
constexpr int kOStep = 3 * 64;        // 192
constexpr int kQSlot = kK * 5 * 64;   // 2560
constexpr int kQStep = 5 * 64;        // 320
constexpr int kRSlot = kK * 64;       // 512
}

typedef float v2 __attribute__((ext_vector_type(2)));

__device__ __forceinline__ v2 mk2(float a, float b) { v2 r; r.x = a; r.y = b; return r; }
__device__ __forceinline__ float fast_rcp(float x) { return __builtin_amdgcn_rcpf(x); }
__device__ __forceinline__ float fast_rsq(float x) { return __builtin_amdgcn_rsqf(x); }

// atan2 for y >= 0, result in [0, pi]. Minimax atan poly on [0,1], err ~1e-5.
__device__ __forceinline__ float atan2_pos(float y, float x) {
  float axx = fabsf(x);
  float mn  = fminf(y, axx);
  float mx  = fmaxf(y, axx);
  float t   = mn * fast_rcp(mx);
  float t2  = t * t;
  float p = fmaf(t2, -0.01172120f, 0.05265332f);
  p = fmaf(t2, p, -0.11643287f);
  p = fmaf(t2, p, 0.19354346f);
  p = fmaf(t2, p, -0.33262347f);
  p = fmaf(t2, p, 0.99997726f);
  p *= t;
  p = (y > axx) ? (1.5707963268f - p) : p;
  p = (x < 0.0f) ? (3.1415926536f - p) : p;
  return p;
}

// accurate, used ONCE per trajectory at init
__device__ __forceinline__ void so3_to_quat_init(float rx, float ry, float rz,
                                                 float& qx, float& qy, float& qz, float& qw) {
  float theta = sqrtf(rx * rx + ry * ry + rz * rz);
  float half  = 0.5f * theta;
  float s     = sinf(half);
  float c     = cosf(half);
  float k     = s / (theta + 1e-8f);
  bool  small = theta < 1e-6f;
  k  = small ? 0.5f : k;
  qw = small ? 1.0f : c;
  qx = k * rx; qy = k * ry; qz = k * rz;
}

// log map, output-only path (w3)
__device__ __forceinline__ void quat_to_so3_fast(float qx, float qy, float qz, float qw,
                                                 float& rx, float& ry, float& rz) {
  float nv2 = qx * qx + qy * qy + qz * qz;
  float nv  = nv2 * fast_rsq(fmaxf(nv2, 1e-20f));   // sqrt(nv2), safe at 0
  float wc  = fminf(fmaxf(qw, -0.999999f), 0.999999f);
  float ang = 2.0f * atan2_pos(nv, wc);
  float k   = ang * fast_rcp(nv + 1e-6f);
  k = (nv < 1e-6f) ? 2.0f : k;
  rx = k * qx; ry = k * qy; rz = k * qz;
}

// Newton renorm from y0=1 (|q|^2 = 1+eps): no transcendental.
__device__ __forceinline__ void renorm(v2& a, v2& b) {
  v2 s = a * a + b * b;
  float c = 1.5f - 0.5f * (s.x + s.y);
  a *= c; b *= c;
}

// quat derivative (x2)
__device__ __forceinline__ void qd_calc(
    v2 q_xy, v2 q_zw, v2 w_xy, float wz, v2& qd_xy, v2& qd_zw) {
  float qx = q_xy.x, qy = q_xy.y, qz = q_zw.x, qw = q_zw.y;
  v2 aq = mk2(qy, -qx);
  v2 pw = mk2(-w_xy.y, w_xy.x);
  qd_xy = qw * w_xy + wz * aq + qz * pw;
  qd_zw = wz * mk2(qw, -qz) + qx * mk2(w_xy.y, -w_xy.x) - qy * w_xy;
}

// accel from a stage quat (raw, 1/M deferred).
__device__ __forceinline__ void acc_q(float qx, float qy, float qz, float qw,
                                      float T2, float TmG,
                                      v2& a_xy, float& az) {
  v2 t_xy = T2 * mk2(qy, -qx);
  a_xy = qw * t_xy + qz * mk2(-t_xy.y, t_xy.x);
  az   = TmG - T2 * (qx * qx + qy * qy);
}

// ---------------- w0: omega + tau, one RK4 step ---------------------
// ships F0=(o2x,o2y,o3x,o3y) F1=(o4x,o4y,ozf,T) F2=(oNx,oNy,ozh,0)
__device__ __forceinline__ void omega_step(
    float4 u, v2& o_xy, float& oz, float4* dst) {
  float m20 = u.x * u.x, m21 = u.y * u.y, m22 = u.z * u.z, m23 = u.w * u.w;
  float sa = m20 + m21, sb = m22 + m23;
  float T   = fminf(kKT * (sa + sb), kTmax);
  float tq1 = kKTA * (sb - sa);
  float tq2 = kKTA * ((m21 + m22) - (m20 + m23));
  float tq3 = kKC  * ((m20 + m22) - (m21 + m23));
  tq1 = __builtin_amdgcn_fmed3f(tq1, -kTq0, kTq0);
  tq2 = __builtin_amdgcn_fmed3f(tq2, -kTq1, kTq1);
  tq3 = __builtin_amdgcn_fmed3f(tq3, -kTq2, kTq2);
  v2    s_xy = mk2(tq1 * kInvJx, tq2 * kInvJx);
  float wdz  = tq3 * kInvJz;          // stage-invariant (Jx==Jy)
  float ozh  = fmaf(kH,  wdz, oz);
  float ozf  = fmaf(kDT, wdz, oz);
  v2 wd1 = s_xy + (kA * oz ) * mk2(-o_xy.y, o_xy.x);
  v2 o2  = o_xy + kH * wd1;
  v2 wd2 = s_xy + (kA * ozh) * mk2(-o2.y, o2.x);
  v2 o3  = o_xy + kH * wd2;
  v2 wd3 = s_xy + (kA * ozh) * mk2(-o3.y, o3.x);
  v2 o4  = o_xy + kDT * wd3;
  v2 wd4 = s_xy + (kA * ozf) * mk2(-o4.y, o4.x);
  dst[0 * 64] = make_float4(o2.x, o2.y, o3.x, o3.y);
  dst[1 * 64] = make_float4(o4.x, o4.y, ozf, T);
  v2 ws = wd2 + wd3;
  o_xy = o_xy + kDT6 * ((wd1 + ws) + (ws + wd4));
  oz = ozf;
  dst[2 * 64] = make_float4(o_xy.x, o_xy.y, ozh, 0.0f);
}

// ---------------- w1: quat chain (no stage renorms, R10a/R13-proven) --
// o1/oz1 loop-carried (exact: = w0's prev o_new/ozf). Ships Q2,Q3,Q4,QN,EX.
__device__ __forceinline__ void quat_step(
    const float4* src, v2& q_xy, v2& q_zw, v2& o1, float& oz1, float4* dst) {
  float4 F0 = src[0 * 64], F1 = src[1 * 64], F2 = src[2 * 64];
  v2 o2 = mk2(F0.x, F0.y), o3 = mk2(F0.z, F0.w), o4 = mk2(F1.x, F1.y);
  float ozf = F1.z, ozh = F2.z;

  v2 qd1_xy, qd1_zw;
  qd_calc(q_xy, q_zw, o1, oz1, qd1_xy, qd1_zw);
  v2 q2_xy = q_xy + kHq * qd1_xy, q2_zw = q_zw + kHq * qd1_zw;
  v2 qd2_xy, qd2_zw;
  qd_calc(q2_xy, q2_zw, o2, ozh, qd2_xy, qd2_zw);
  v2 q3_xy = q_xy + kHq * qd2_xy, q3_zw = q_zw + kHq * qd2_zw;
  v2 qd3_xy, qd3_zw;
  qd_calc(q3_xy, q3_zw, o3, ozh, qd3_xy, qd3_zw);
  v2 q4_xy = q_xy + kDTq * qd3_xy, q4_zw = q_zw + kDTq * qd3_zw;
  v2 qd4_xy, qd4_zw;
  qd_calc(q4_xy, q4_zw, o4, ozf, qd4_xy, qd4_zw);

  dst[0 * 64] = make_float4(q2_xy.x, q2_xy.y, q2_zw.x, q2_zw.y);
  dst[1 * 64] = make_float4(q3_xy.x, q3_xy.y, q3_zw.x, q3_zw.y);
  dst[2 * 64] = make_float4(q4_xy.x, q4_xy.y, q4_zw.x, q4_zw.y);
  v2 qxy23 = qd2_xy + qd3_xy;
  q_xy = q_xy + kDT6q * ((qd1_xy + qxy23) + (qxy23 + qd4_xy));
  v2 qzw23 = qd2_zw + qd3_zw;
  q_zw = q_zw + kDT6q * ((qd1_zw + qzw23) + (qzw23 + qd4_zw));
  renorm(q_xy, q_zw);               // loop-carried renorm kept
  dst[3 * 64] = make_float4(q_xy.x, q_xy.y, q_zw.x, q_zw.y);
  dst[4 * 64] = make_float4(F2.x, F2.y, ozf, F1.w);   // EX=(oN,ozN,T)
  o1 = mk2(F2.x, F2.y); oz1 = ozf;  // carry for next step (exact)
}

// ---------------- w2: accels + p/v + ov0 store; buffers (vy,vz) -------
__device__ __forceinline__ void accpv_step(
    const float4* qsrc,
    v2& p_xy, float& pz, v2& v_xy, float& vz,
    float& qpx, float& qpy, float& qpz, float& qpw,
    float4* ovp, v2& vb_out) {
  float4 Q2 = qsrc[0 * 64], Q3 = qsrc[1 * 64], Q4 = qsrc[2 * 64],
         QN = qsrc[3 * 64], EX = qsrc[4 * 64];
  float T  = EX.w;
  float T2 = T + T, TmG = T - kMG;

  v2 a1, a2, a3, a4; float az1, az2, az3, az4;
  acc_q(qpx, qpy, qpz, qpw, T2, TmG, a1, az1);
  acc_q(Q2.x, Q2.y, Q2.z, Q2.w, T2, TmG, a2, az2);
  acc_q(Q3.x, Q3.y, Q3.z, Q3.w, T2, TmG, a3, az3);
  acc_q(Q4.x, Q4.y, Q4.z, Q4.w, T2, TmG, a4, az4);

  v2 t23 = a2 + a3;
  v2 Apos = a1 + t23;
  v2 Avel = Apos + t23 + a4;
  p_xy = p_xy + kDT * v_xy;  p_xy = p_xy + kPC * Apos;
  float az23 = az2 + az3;
  float Aposz = az1 + az23;
  float Avelz = Aposz + az23 + az4;
  pz = fmaf(kDT, vz, pz);  pz = fmaf(kPC, Aposz, pz);
  v_xy = v_xy + kVC * Avel;
  vz   = fmaf(kVC, Avelz, vz);

  ovp[0] = make_float4(p_xy.x, p_xy.y, pz, v_xy.x);
  vb_out = mk2(v_xy.y, vz);

  qpx = QN.x; qpy = QN.y; qpz = QN.z; qpw = QN.w;
}

// ---------------- w3: logmap + ov2 store; ships (rx,ry) ---------------
__device__ __forceinline__ void logst_step(
    const float4* qsrc, float4* rdst, float4* ovp) {
  float4 QN = qsrc[3 * 64];
  float4 EX = qsrc[4 * 64];
  float rx, ry, rz;
  quat_to_so3_fast(QN.x, QN.y, QN.z, QN.w, rx, ry, rz);
  ovp[2]  = make_float4(rz, EX.x, EX.y, EX.z);   // (rz, oNx, oNy, ozN)
  rdst[0] = make_float4(rx, ry, 0.0f, 0.0f);
}

__global__ __launch_bounds__(256) void quad_rk4_kernel(
    const float* __restrict__ x0,
    const float* __restrict__ u_seq,
    float* __restrict__ out) {
  // obuf [2][8 steps][3 fields][64] = 48KB   (reader w1, lag1)
  // qbuf [2][8 steps][5 fields][64] = 80KB   (readers w2+w3, lag2)
  // rbuf [2][8 steps][64]           = 16KB   (reader w2, lag1 behind w3)
  __shared__ float4 obuf[2 * kOSlot];
  __shared__ float4 qbuf[2 * kQSlot];
  __shared__ float4 rbuf[2 * kRSlot];

  const int lane = threadIdx.x & 63;
  const int wid  = threadIdx.x >> 6;
  const int b    = blockIdx.x * 64 + lane;

  const float4* xv = reinterpret_cast<const float4*>(x0) + (size_t)b * 3;
  float4 s0 = xv[0], s1 = xv[1], s2 = xv[2];
  const float4* uv = reinterpret_cast<const float4*>(u_seq) + (size_t)b * kN;
  float4* ov = reinterpret_cast<float4*>(out) + (size_t)b * kN * 3;

  // per-wave persistent state (only the owning wave touches each)
  v2 o_xy; float oz = 0.0f;                       // w0
  float4 ug[kK], un[kK];
  v2 q_xy, q_zw, o1c; float oz1c = 0.0f;          // w1
  v2 p_xy, v_xy; float pz = 0.0f, vz = 0.0f;      // w2
  float qpx = 0.0f, qpy = 0.0f, qpz = 0.0f, qpw = 1.0f;
  v2 vb[kK];                                      // w2's (vy,vz) buffer

  if (wid == 0) {
    o_xy = mk2(s2.y, s2.z); oz = s2.w;
#pragma unroll
    for (int i = 0; i < kK; ++i) ug[i] = uv[i];
  } else if (wid == 1) {
    float a, bb, c, d;
    so3_to_quat_init(s1.z, s1.w, s2.x, a, bb, c, d);
    q_xy = mk2(a, bb); q_zw = mk2(c, d);
    o1c = mk2(s2.y, s2.z); oz1c = s2.w;           // exact initial omega
  } else if (wid == 2) {
    p_xy = mk2(s0.x, s0.y); pz = s0.z;
    v_xy = mk2(s0.w, s1.x); vz = s1.y;
    so3_to_quat_init(s1.z, s1.w, s2.x, qpx, qpy, qpz, qpw);
  }

  for (int s = 0; s < kG + 3; ++s) {
    if (wid == 0) {
      if (s < kG) {
        int gn = (s + 1 < kG) ? (s + 1) * kK : (kG - 1) * kK;
#pragma unroll
        for (int i = 0; i < kK; ++i) un[i] = uv[gn + i];
        float4* dst = &obuf[(s & 1) * kOSlot + lane];
#pragma unroll
        for (int i = 0; i < kK; ++i)
          omega_step(ug[i], o_xy, oz, dst + i * kOStep);
#pragma unroll
        for (int i = 0; i < kK; ++i) ug[i] = un[i];
      }
    } else if (wid == 1) {
      if (s >= 1 && s <= kG) {
        int g = s - 1;
        const float4* src = &obuf[(g & 1) * kOSlot + lane];
        float4*       dst = &qbuf[(g & 1) * kQSlot + lane];
#pragma unroll
        for (int i = 0; i < kK; ++i)
          quat_step(src + i * kOStep, q_xy, q_zw, o1c, oz1c, dst + i * kQStep);
      }
    } else if (wid == 2) {
      if (s >= 3) {          // ov1 stores for group s-3 (vb regs + rbuf)
        int g = s - 3;
        const float4* rsrc = &rbuf[(g & 1) * kRSlot + lane];
        float4* ovp = ov + (size_t)(g * kK) * 3;
#pragma unroll
        for (int i = 0; i < kK; ++i) {
          float4 R = rsrc[i * 64];
          ovp[i * 3 + 1] = make_float4(vb[i].x, vb[i].y, R.x, R.y);
        }
      }
      if (s >= 2 && s <= kG + 1) {    // acc/pv for group s-2
        int g = s - 2;
        const float4* qsrc = &qbuf[(g & 1) * kQSlot + lane];
        float4* ovp = ov + (size_t)(g * kK) * 3;
#pragma unroll
        for (int i = 0; i < kK; ++i)
          accpv_step(qsrc + i * kQStep, p_xy, pz, v_xy, vz,
                     qpx, qpy, qpz, qpw, ovp + i * 3, vb[i]);
      }
    } else {
      if (s >= 2 && s <= kG + 1) {    // logmap + ov2 for group s-2
        int g = s - 2;
        const float4* qsrc = &qbuf[(g & 1) * kQSlot + lane];
        float4*       rdst = &rbuf[(g & 1) * kRSlot + lane];
        float4* ovp = ov + (size_t)(g * kK) * 3;
#pragma unroll
        for (int i = 0; i < kK; ++i)
          logst_step(qsrc + i * kQStep, rdst + i * 64, ovp + i * 3);
      }
    }
    __syncthreads();   // 35 barriers total; slots = lag+1 on every buffer
  }
}

extern "C" void kernel_launch(void* const* d_in, const int* in_sizes, int n_in,
                              void* d_out, int out_size, void* d_ws, size_t ws_size,
                              hipStream_t stream) {
  const float* x0    = (const float*)d_in[0];   // (8192, 12)
  const float* u_seq = (const float*)d_in[1];   // (8192, 256, 4)
  float*       out   = (float*)d_out;           // (8192, 256, 12)
  (void)in_sizes; (void)n_in; (void)out_size; (void)d_ws; (void)ws_size;

  dim3 block(256);            // w0 omega | w1 quat | w2 acc+pv | w3 logmap
  dim3 grid(kB / 64);         // 128 blocks, 64 trajectories each
  quad_rk4_kernel<<<grid, block, 0, stream>>>(x0, u_seq, out);
}

// Round 12
// 175.123 us; speedup vs baseline: 1.1293x; 1.0126x over previous
//
#include <hip/hip_runtime.h>
#include <math.h>

// PhysQuadModel: batched RK4 rollout of quadrotor dynamics.
// Ladder (rocprof): R6 192 | R7 125 | R8 203 | R9 140 | R10 136 | R11 114
//   | R12 95 | R13 86 | R14 104 (flag sync regressed) | R15 83 (4-wave, K=8).
// R15 decomposition: barrier cost ~230 cyc/slot (~30/step at K=8, solved);
//   wall 711 cyc/step ~= critical-wave (w1) stream at the empirical lone-wave
//   cadence (~5.5 cyc/inst) + per-step LDS-read latency exposure.
// R16 (this): math BIT-IDENTICAL to R15 (absmax must be exactly 0.3125):
//   1) re-route shipping: w0 writes (oN,ozN,T) straight to tbuf (3 slots);
//      obuf -> 2 fields (ozh in F1.w); w1 writes only Q2,Q3,Q4,QN (4 not 5).
//   2) explicit intra-slot prefetch in w1/w2: issue step i+1's ds_reads
//      before computing step i -> ds latency overlaps the dependent chain.
//   LDS: obuf 32KB + qbuf 64KB + tbuf 24KB + rbuf 16KB = 136KB.

namespace {
constexpr int   kB    = 8192;
constexpr int   kN    = 256;
constexpr int   kK    = 8;               // steps per group
constexpr int   kG    = kN / kK;         // 32 groups
constexpr float kDT   = 0.01f;
constexpr float kMG   = 0.033f * 9.81f;        // M*G
constexpr float kTmax = 1.9f * 0.033f * 9.81f; // 0.6150870
constexpr float kKT   = 3.8e-08f;
constexpr float kKC   = 3.8e-11f;
constexpr float kKTA  = kKT * 0.04f;           // KT*ARM
constexpr float kInvM = 1.0f / 0.033f;
constexpr float kJx   = 1.4e-05f, kJz = 2.17e-05f;
constexpr float kInvJx = 1.0f / 1.4e-05f;
constexpr float kInvJz = 1.0f / 2.17e-05f;
constexpr float kA    = (kJz - kJx) * kInvJx;  // 0.55 (Jx==Jy)
constexpr float kTq0  = 0.009f, kTq1 = 0.009f, kTq2 = 0.002f;
constexpr float kH    = 0.005f;                // 0.5*dt   (omega euler)
constexpr float kHq   = 0.0025f;               // 0.5*dt*0.5 (qd' = 2*qd)
constexpr float kDTq  = 0.005f;                // dt*0.5   (stage-4 quat)
constexpr float kDT6  = 0.0016666667f;         // dt/6
constexpr float kDT6q = 0.5f * kDT6;           // dt/12
constexpr float kVC   = kDT6 * kInvM;          // raw accel -> vel
constexpr float kPC   = kDT6 * kDT * kInvM;    // raw accel -> pos
// LDS strides (float4 units)
constexpr int kOStep = 2 * 64;        // 128
constexpr int kOSlot = kK * kOStep;   // 1024  (2 slots = 32KB)
constexpr int kQStep = 4 * 64;        // 256
constexpr int kQSlot = kK * kQStep;   // 2048  (2 slots = 64KB)
constexpr int kTStep = 64;
constexpr int kTSlot = kK * kTStep;   // 512   (3 slots = 24KB)
constexpr int kRSlot = kK * 64;       // 512   (2 slots = 16KB)
}

typedef float v2 __attribute__((ext_vector_type(2)));

__device__ __forceinline__ v2 mk2(float a, float b) { v2 r; r.x = a; r.y = b; return r; }
__device__ __forceinline__ float fast_rcp(float x) { return __builtin_amdgcn_rcpf(x); }
__device__ __forceinline__ float fast_rsq(float x) { return __builtin_amdgcn_rsqf(x); }

// atan2 for y >= 0, result in [0, pi]. Minimax atan poly on [0,1], err ~1e-5.
__device__ __forceinline__ float atan2_pos(float y, float x) {
  float axx = fabsf(x);
  float mn  = fminf(y, axx);
  float mx  = fmaxf(y, axx);
  float t   = mn * fast_rcp(mx);
  float t2  = t * t;
  float p = fmaf(t2, -0.01172120f, 0.05265332f);
  p = fmaf(t2, p, -0.11643287f);
  p = fmaf(t2, p, 0.19354346f);
  p = fmaf(t2, p, -0.33262347f);
  p = fmaf(t2, p, 0.99997726f);
  p *= t;
  p = (y > axx) ? (1.5707963268f - p) : p;
  p = (x < 0.0f) ? (3.1415926536f - p) : p;
  return p;
}

// accurate, used ONCE per trajectory at init
__device__ __forceinline__ void so3_to_quat_init(float rx, float ry, float rz,
                                                 float& qx, float& qy, float& qz, float& qw) {
  float theta = sqrtf(rx * rx + ry * ry + rz * rz);
  float half  = 0.5f * theta;
  float s     = sinf(half);
  float c     = cosf(half);
  float k     = s / (theta + 1e-8f);
  bool  small = theta < 1e-6f;
  k  = small ? 0.5f : k;
  qw = small ? 1.0f : c;
  qx = k * rx; qy = k * ry; qz = k * rz;
}

// log map, output-only path (w3)
__device__ __forceinline__ void quat_to_so3_fast(float qx, float qy, float qz, float qw,
                                                 float& rx, float& ry, float& rz) {
  float nv2 = qx * qx + qy * qy + qz * qz;
  float nv  = nv2 * fast_rsq(fmaxf(nv2, 1e-20f));   // sqrt(nv2), safe at 0
  float wc  = fminf(fmaxf(qw, -0.999999f), 0.999999f);
  float ang = 2.0f * atan2_pos(nv, wc);
  float k   = ang * fast_rcp(nv + 1e-6f);
  k = (nv < 1e-6f) ? 2.0f : k;
  rx = k * qx; ry = k * qy; rz = k * qz;
}

// Newton renorm from y0=1 (|q|^2 = 1+eps): no transcendental.
__device__ __forceinline__ void renorm(v2& a, v2& b) {
  v2 s = a * a + b * b;
  float c = 1.5f - 0.5f * (s.x + s.y);
  a *= c; b *= c;
}

// quat derivative (x2)
__device__ __forceinline__ void qd_calc(
    v2 q_xy, v2 q_zw, v2 w_xy, float wz, v2& qd_xy, v2& qd_zw) {
  float qx = q_xy.x, qy = q_xy.y, qz = q_zw.x, qw = q_zw.y;
  v2 aq = mk2(qy, -qx);
  v2 pw = mk2(-w_xy.y, w_xy.x);
  qd_xy = qw * w_xy + wz * aq + qz * pw;
  qd_zw = wz * mk2(qw, -qz) + qx * mk2(w_xy.y, -w_xy.x) - qy * w_xy;
}

// accel from a stage quat (raw, 1/M deferred).
__device__ __forceinline__ void acc_q(float qx, float qy, float qz, float qw,
                                      float T2, float TmG,
                                      v2& a_xy, float& az) {
  v2 t_xy = T2 * mk2(qy, -qx);
  a_xy = qw * t_xy + qz * mk2(-t_xy.y, t_xy.x);
  az   = TmG - T2 * (qx * qx + qy * qy);
}

// ---------------- w0: omega + tau, one RK4 step ---------------------
// obuf: F0=(o2x,o2y,o3x,o3y) F1=(o4x,o4y,ozf,ozh); tbuf: (oNx,oNy,ozN,T)
__device__ __forceinline__ void omega_step(
    float4 u, v2& o_xy, float& oz, float4* dst, float4* tdst) {
  float m20 = u.x * u.x, m21 = u.y * u.y, m22 = u.z * u.z, m23 = u.w * u.w;
  float sa = m20 + m21, sb = m22 + m23;
  float T   = fminf(kKT * (sa + sb), kTmax);
  float tq1 = kKTA * (sb - sa);
  float tq2 = kKTA * ((m21 + m22) - (m20 + m23));
  float tq3 = kKC  * ((m20 + m22) - (m21 + m23));
  tq1 = __builtin_amdgcn_fmed3f(tq1, -kTq0, kTq0);
  tq2 = __builtin_amdgcn_fmed3f(tq2, -kTq1, kTq1);
  tq3 = __builtin_amdgcn_fmed3f(tq3, -kTq2, kTq2);
  v2    s_xy = mk2(tq1 * kInvJx, tq2 * kInvJx);
  float wdz  = tq3 * kInvJz;          // stage-invariant (Jx==Jy)
  float ozh  = fmaf(kH,  wdz, oz);
  float ozf  = fmaf(kDT, wdz, oz);
  v2 wd1 = s_xy + (kA * oz ) * mk2(-o_xy.y, o_xy.x);
  v2 o2  = o_xy + kH * wd1;
  v2 wd2 = s_xy + (kA * ozh) * mk2(-o2.y, o2.x);
  v2 o3  = o_xy + kH * wd2;
  v2 wd3 = s_xy + (kA * ozh) * mk2(-o3.y, o3.x);
  v2 o4  = o_xy + kDT * wd3;
  v2 wd4 = s_xy + (kA * ozf) * mk2(-o4.y, o4.x);
  dst[0 * 64] = make_float4(o2.x, o2.y, o3.x, o3.y);
  dst[1 * 64] = make_float4(o4.x, o4.y, ozf, ozh);
  v2 ws = wd2 + wd3;
  o_xy = o_xy + kDT6 * ((wd1 + ws) + (ws + wd4));
  oz = ozf;
  tdst[0] = make_float4(o_xy.x, o_xy.y, oz, T);
}

// ---------------- w1: quat chain (no stage renorms, R13-proven) -------
// operands passed by VALUE (prefetched by caller). o1/oz1 from TB (exact:
// = w0's o_new/ozf of the previous step). Ships Q2,Q3,Q4,QN only.
__device__ __forceinline__ void quat_step(
    float4 F0, float4 F1, v2& q_xy, v2& q_zw, v2& o1, float& oz1,
    float4* dst, float4 TB) {
  v2 o2 = mk2(F0.x, F0.y), o3 = mk2(F0.z, F0.w), o4 = mk2(F1.x, F1.y);
  float ozf = F1.z, ozh = F1.w;

  v2 qd1_xy, qd1_zw;
  qd_calc(q_xy, q_zw, o1, oz1, qd1_xy, qd1_zw);
  v2 q2_xy = q_xy + kHq * qd1_xy, q2_zw = q_zw + kHq * qd1_zw;
  v2 qd2_xy, qd2_zw;
  qd_calc(q2_xy, q2_zw, o2, ozh, qd2_xy, qd2_zw);
  v2 q3_xy = q_xy + kHq * qd2_xy, q3_zw = q_zw + kHq * qd2_zw;
  v2 qd3_xy, qd3_zw;
  qd_calc(q3_xy, q3_zw, o3, ozh, qd3_xy, qd3_zw);
  v2 q4_xy = q_xy + kDTq * qd3_xy, q4_zw = q_zw + kDTq * qd3_zw;
  v2 qd4_xy, qd4_zw;
  qd_calc(q4_xy, q4_zw, o4, ozf, qd4_xy, qd4_zw);

  dst[0 * 64] = make_float4(q2_xy.x, q2_xy.y, q2_zw.x, q2_zw.y);
  dst[1 * 64] = make_float4(q3_xy.x, q3_xy.y, q3_zw.x, q3_zw.y);
  dst[2 * 64] = make_float4(q4_xy.x, q4_xy.y, q4_zw.x, q4_zw.y);
  v2 qxy23 = qd2_xy + qd3_xy;
  q_xy = q_xy + kDT6q * ((qd1_xy + qxy23) + (qxy23 + qd4_xy));
  v2 qzw23 = qd2_zw + qd3_zw;
  q_zw = q_zw + kDT6q * ((qd1_zw + qzw23) + (qzw23 + qd4_zw));
  renorm(q_xy, q_zw);               // loop-carried renorm kept
  dst[3 * 64] = make_float4(q_xy.x, q_xy.y, q_zw.x, q_zw.y);
  o1 = mk2(TB.x, TB.y); oz1 = TB.z; // carry for next step (exact)
}

// ---------------- w2: accels + p/v + ov0 store; buffers (vy,vz) -------
__device__ __forceinline__ void accpv_step(
    float4 Q2, float4 Q3, float4 Q4, float4 QN, float T,
    v2& p_xy, float& pz, v2& v_xy, float& vz,
    float& qpx, float& qpy, float& qpz, float& qpw,
    float4* ovp, v2& vb_out) {
  float T2 = T + T, TmG = T - kMG;

  v2 a1, a2, a3, a4; float az1, az2, az3, az4;
  acc_q(qpx, qpy, qpz, qpw, T2, TmG, a1, az1);
  acc_q(Q2.x, Q2.y, Q2.z, Q2.w, T2, TmG, a2, az2);
  acc_q(Q3.x, Q3.y, Q3.z, Q3.w, T2, TmG, a3, az3);
  acc_q(Q4.x, Q4.y, Q4.z, Q4.w, T2, TmG, a4, az4);

  v2 t23 = a2 + a3;
  v2 Apos = a1 + t23;
  v2 Avel = Apos + t23 + a4;
  p_xy = p_xy + kDT * v_xy;  p_xy = p_xy + kPC * Apos;
  float az23 = az2 + az3;
  float Aposz = az1 + az23;
  float Avelz = Aposz + az23 + az4;
  pz = fmaf(kDT, vz, pz);  pz = fmaf(kPC, Aposz, pz);
  v_xy = v_xy + kVC * Avel;
  vz   = fmaf(kVC, Avelz, vz);

  ovp[0] = make_float4(p_xy.x, p_xy.y, pz, v_xy.x);
  vb_out = mk2(v_xy.y, vz);

  qpx = QN.x; qpy = QN.y; qpz = QN.z; qpw = QN.w;
}

__global__ __launch_bounds__(256) void quad_rk4_kernel(
    const float* __restrict__ x0,
    const float* __restrict__ u_seq,
    float* __restrict__ out) {
  __shared__ float4 obuf[2 * kOSlot];   // 32KB  (reader w1, lag1)
  __shared__ float4 qbuf[2 * kQSlot];   // 64KB  (readers w2+w3, lag2)
  __shared__ float4 tbuf[3 * kTSlot];   // 24KB  (readers w1 lag1, w2/w3 lag2)
  __shared__ float4 rbuf[2 * kRSlot];   // 16KB  (reader w2, lag1 behind w3)

  const int lane = threadIdx.x & 63;
  const int wid  = threadIdx.x >> 6;
  const int b    = blockIdx.x * 64 + lane;

  const float4* xv = reinterpret_cast<const float4*>(x0) + (size_t)b * 3;
  float4 s0 = xv[0], s1 = xv[1], s2 = xv[2];
  const float4* uv = reinterpret_cast<const float4*>(u_seq) + (size_t)b * kN;
  float4* ov = reinterpret_cast<float4*>(out) + (size_t)b * kN * 3;

  // per-wave persistent state
  v2 o_xy; float oz = 0.0f;                       // w0
  float4 ug[kK], un[kK];
  v2 q_xy, q_zw, o1c; float oz1c = 0.0f;          // w1
  v2 p_xy, v_xy; float pz = 0.0f, vz = 0.0f;      // w2
  float qpx = 0.0f, qpy = 0.0f, qpz = 0.0f, qpw = 1.0f;
  v2 vb[kK];                                      // w2's (vy,vz) buffer

  if (wid == 0) {
    o_xy = mk2(s2.y, s2.z); oz = s2.w;
#pragma unroll
    for (int i = 0; i < kK; ++i) ug[i] = uv[i];
  } else if (wid == 1) {
    float a, bb, c, d;
    so3_to_quat_init(s1.z, s1.w, s2.x, a, bb, c, d);
    q_xy = mk2(a, bb); q_zw = mk2(c, d);
    o1c = mk2(s2.y, s2.z); oz1c = s2.w;           // exact initial omega
  } else if (wid == 2) {
    p_xy = mk2(s0.x, s0.y); pz = s0.z;
    v_xy = mk2(s0.w, s1.x); vz = s1.y;
    so3_to_quat_init(s1.z, s1.w, s2.x, qpx, qpy, qpz, qpw);
  }

  for (int s = 0; s < kG + 3; ++s) {
    if (wid == 0) {
      if (s < kG) {
        int gn = (s + 1 < kG) ? (s + 1) * kK : (kG - 1) * kK;
#pragma unroll
        for (int i = 0; i < kK; ++i) un[i] = uv[gn + i];
        float4* dst  = &obuf[(s & 1) * kOSlot + lane];
        float4* tdst = &tbuf[(s % 3) * kTSlot + lane];
#pragma unroll
        for (int i = 0; i < kK; ++i)
          omega_step(ug[i], o_xy, oz, dst + i * kOStep, tdst + i * kTStep);
#pragma unroll
        for (int i = 0; i < kK; ++i) ug[i] = un[i];
      }
    } else if (wid == 1) {
      if (s >= 1 && s <= kG) {
        int g = s - 1;
        const float4* src  = &obuf[(g & 1) * kOSlot + lane];
        const float4* tsrc = &tbuf[(g % 3) * kTSlot + lane];
        float4*       dst  = &qbuf[(g & 1) * kQSlot + lane];
        // prefetch pipeline: step i+1's operands load during step i compute
        float4 F0 = src[0], F1 = src[64], TB = tsrc[0];
#pragma unroll
        for (int i = 0; i < kK; ++i) {
          float4 nF0, nF1, nTB;
          if (i + 1 < kK) {
            nF0 = src[(i + 1) * kOStep];
            nF1 = src[(i + 1) * kOStep + 64];
            nTB = tsrc[(i + 1) * kTStep];
          }
          quat_step(F0, F1, q_xy, q_zw, o1c, oz1c, dst + i * kQStep, TB);
          F0 = nF0; F1 = nF1; TB = nTB;
        }
      }
    } else if (wid == 2) {
      if (s >= 3) {          // ov1 stores for group s-3 (vb regs + rbuf)
        int g = s - 3;
        const float4* rsrc = &rbuf[(g & 1) * kRSlot + lane];
        float4* ovp = ov + (size_t)(g * kK) * 3;
#pragma unroll
        for (int i = 0; i < kK; ++i) {
          float4 R = rsrc[i * 64];
          ovp[i * 3 + 1] = make_float4(vb[i].x, vb[i].y, R.x, R.y);
        }
      }
      if (s >= 2 && s <= kG + 1) {    // acc/pv for group s-2
        int g = s - 2;
        const float4* qsrc = &qbuf[(g & 1) * kQSlot + lane];
        const float4* tsrc = &tbuf[(g % 3) * kTSlot + lane];
        float4* ovp = ov + (size_t)(g * kK) * 3;
        float4 Q2 = qsrc[0], Q3 = qsrc[64], Q4 = qsrc[128], QN = qsrc[192];
        float4 TB = tsrc[0];
#pragma unroll
        for (int i = 0; i < kK; ++i) {
          float4 n2, n3, n4, nN, nT;
          if (i + 1 < kK) {
            const float4* nq = qsrc + (i + 1) * kQStep;
            n2 = nq[0]; n3 = nq[64]; n4 = nq[128]; nN = nq[192];
            nT = tsrc[(i + 1) * kTStep];
          }
          accpv_step(Q2, Q3, Q4, QN, TB.w, p_xy, pz, v_xy, vz,
                     qpx, qpy, qpz, qpw, ovp + i * 3, vb[i]);
          Q2 = n2; Q3 = n3; Q4 = n4; QN = nN; TB = nT;
        }
      }
    } else {
      if (s >= 2 && s <= kG + 1) {    // logmap + ov2 for group s-2
        int g = s - 2;
        const float4* qsrc = &qbuf[(g & 1) * kQSlot + lane];
        const float4* tsrc = &tbuf[(g % 3) * kTSlot + lane];
        float4*       rdst = &rbuf[(g & 1) * kRSlot + lane];
        float4* ovp = ov + (size_t)(g * kK) * 3;
#pragma unroll
        for (int i = 0; i < kK; ++i) {
          float4 QN = qsrc[i * kQStep + 192];
          float4 TB = tsrc[i * kTStep];
          float rx, ry, rz;
          quat_to_so3_fast(QN.x, QN.y, QN.z, QN.w, rx, ry, rz);
          ovp[i * 3 + 2] = make_float4(rz, TB.x, TB.y, TB.z);
          rdst[i * 64]   = make_float4(rx, ry, 0.0f, 0.0f);
        }
      }
    }
    __syncthreads();   // 35 barriers; slots = lag+1 on every buffer
  }
}

extern "C" void kernel_launch(void* const* d_in, const int* in_sizes, int n_in,
                              void* d_out, int out_size, void* d_ws, size_t ws_size,
                              hipStream_t stream) {
  const float* x0    = (const float*)d_in[0];   // (8192, 12)
  const float* u_seq = (const float*)d_in[1];   // (8192, 256, 4)
  float*       out   = (float*)d_out;           // (8192, 256, 12)
  (void)in_sizes; (void)n_in; (void)out_size; (void)d_ws; (void)ws_size;

  dim3 block(256);            // w0 omega | w1 quat | w2 acc+pv | w3 logmap
  dim3 grid(kB / 64);         // 128 blocks, 64 trajectories each
  quad_rk4_kernel<<<grid, block, 0, stream>>>(x0, u_seq, out);
}